// Round 7
// baseline (112.568 us; speedup 1.0000x reference)
//
#include <hip/hip_runtime.h>
#include <math.h>

constexpr int N = 4096;
constexpr int D = 128;

// ws layout (bytes)
constexpr size_t XBF_OFF = 0;                        // bf16 X image, 4096 x 256 B, XOR-swizzled (1 MB)
constexpr size_t TAB_OFF = (size_t)1 << 20;          // float4 tab[64][4096] = {gB, gQ, g0, e0} (4 MB)
constexpr size_t ACC_OFF = (size_t)5 << 20;          // float acc5[5][4096] = {U, W, V, P1, P2} (80 KB)
constexpr size_t LSD_OFF = ACC_OFF + 5 * N * 4;      // float lsdiag[4096] (16 KB)
constexpr size_t SUM_OFF = LSD_OFF + N * 4;          // float4 sums[64] = {Sg0, SgB, SgQ, Ce0} (1 KB)
constexpr size_t CNT_OFF = SUM_OFF + 64 * 16;        // u32 cnt[64] (256 B)
constexpr size_t PRM_OFF = CNT_OFF + 64 * 4;         // u16 perm[64][128] (16 KB)

typedef __attribute__((ext_vector_type(8))) short short8;
typedef __attribute__((ext_vector_type(4))) float floatx4;
typedef __attribute__((address_space(1))) unsigned int gu32;
typedef __attribute__((address_space(3))) unsigned int lu32;

__device__ inline unsigned f2bf(float f) {
  unsigned u = __builtin_bit_cast(unsigned, f);
  return (u + 0x7FFFu + ((u >> 16) & 1u)) >> 16;   // RNE
}

// ---- K1: per-class row lists + coef table + class sums + bf16 image + diag logs + zeroing ----
__global__ __launch_bounds__(256) void k1_prep(
    const float* __restrict__ X, const int* __restrict__ labels,
    char* __restrict__ ws, float* __restrict__ out,
    float B0, float B1, float B2, float B3,
    float Q0, float Q1, float Q2, float Q3) {
  const int b = blockIdx.x, tid = threadIdx.x;
  if (b < 64) {
    const int t = b;
    __shared__ unsigned cursor;
    __shared__ float red[4][4];
    if (tid == 0) cursor = 0u;
    __syncthreads();
    float4* tab = (float4*)(ws + TAB_OFF) + (size_t)t * N;
    unsigned short* prm = (unsigned short*)(ws + PRM_OFF) + t * 128;
    float sg0 = 0.f, sgB = 0.f, sgQ = 0.f, ce0 = 0.f;
#pragma unroll 4
    for (int k = 0; k < 16; ++k) {
      const int j = k * 256 + tid;
      const int4 L = ((const int4*)labels)[j];
      const bool e0 = (t == L.x), e1 = (t == L.y), e2 = (t == L.z), e3 = (t == L.w);
      const bool n1 = e3 && !e2, n2 = e2 && !e1, n3 = e1 && !e0;
      const float g0 = (e3 ? 0.f : 1.f) + (n1 ? 1.f : 0.f) + (n2 ? 1.f : 0.f) + (n3 ? 1.f : 0.f);
      const float gB = (e3 ? 0.f : B0) + (n1 ? B1 : 0.f) + (n2 ? B2 : 0.f) + (n3 ? B3 : 0.f);
      const float gQ = (e3 ? 0.f : Q0) + (n1 ? Q1 : 0.f) + (n2 ? Q2 : 0.f) + (n3 ? Q3 : 0.f);
      tab[j] = make_float4(gB, gQ, g0, e0 ? 1.f : 0.f);
      sg0 += g0; sgB += gB; sgQ += gQ; ce0 += e0 ? 1.f : 0.f;
      if (e0) {
        const unsigned s = atomicAdd(&cursor, 1u);
        if (s < 128u) prm[s] = (unsigned short)j;
      }
    }
    const int w = tid >> 6, lane = tid & 63;
#pragma unroll
    for (int s = 1; s <= 32; s <<= 1) {
      sg0 += __shfl_xor(sg0, s, 64); sgB += __shfl_xor(sgB, s, 64);
      sgQ += __shfl_xor(sgQ, s, 64); ce0 += __shfl_xor(ce0, s, 64);
    }
    if (lane == 0) { red[w][0] = sg0; red[w][1] = sgB; red[w][2] = sgQ; red[w][3] = ce0; }
    __syncthreads();
    if (tid == 0) {
      float* sums = (float*)(ws + SUM_OFF);
      sums[t * 4 + 0] = red[0][0] + red[1][0] + red[2][0] + red[3][0];
      sums[t * 4 + 1] = red[0][1] + red[1][1] + red[2][1] + red[3][1];
      sums[t * 4 + 2] = red[0][2] + red[1][2] + red[2][2] + red[3][2];
      sums[t * 4 + 3] = red[0][3] + red[1][3] + red[2][3] + red[3][3];
      const unsigned c = cursor;
      ((unsigned*)(ws + CNT_OFF))[t] = c < 128u ? c : 128u;
    }
  } else if (b < 320) {
    const int task = (b - 64) * 256 + tid;       // 0 .. 65535
    const int r   = task >> 4;
    const int blk = task & 15;
    const float4 x0 = *(const float4*)&X[r * D + blk * 8];
    const float4 x1 = *(const float4*)&X[r * D + blk * 8 + 4];
    uint4 wv;
    wv.x = f2bf(x0.x) | (f2bf(x0.y) << 16);
    wv.y = f2bf(x0.z) | (f2bf(x0.w) << 16);
    wv.z = f2bf(x1.x) | (f2bf(x1.y) << 16);
    wv.w = f2bf(x1.z) | (f2bf(x1.w) << 16);
    *(uint4*)(ws + XBF_OFF + (size_t)r * 256 + ((blk ^ (r & 15)) * 16)) = wv;
  } else if (b < 336) {
    const int i = (b - 320) * 256 + tid;         // 0 .. 4095
    const float* xr = X + i * D;
    float s = 0.f;
#pragma unroll
    for (int c = 0; c < 32; ++c) {
      const float4 v = ((const float4*)xr)[c];
      s += v.x * v.x + v.y * v.y + v.z * v.z + v.w * v.w;
    }
    ((float*)(ws + LSD_OFF))[i] = __logf(s + 1e-6f);
  } else {
    const int idx = (b - 336) * 256 + tid;       // 0 .. 20479 == 5*4096
    ((float*)(ws + ACC_OFF))[idx] = 0.f;
    if (idx == 0) out[0] = 0.f;
  }
}

// ---- phaseA: one (class, row-chunk, j-tile) per block; 64x128 tile; LDS coef slice ----
__global__ __launch_bounds__(256, 3) void logratio_phaseA(
    const char* __restrict__ ws_ro, float* acc5) {

  const int jb = blockIdx.x;
  const int t = blockIdx.y >> 1, chunk = blockIdx.y & 1;
  const int cnt = (int)((const unsigned*)(ws_ro + CNT_OFF))[t];
  const int active = min(cnt - chunk * 64, 64);
  if (active <= 0) return;                       // uniform per block, before any barrier

  __shared__ __align__(16) char smem[51200];     // [0,32K) B-tile; [32K,48K) A-tile; [48K,50K) coef slice
  const int tid = threadIdx.x;
  const int w = tid >> 6, lane = tid & 63;
  const int lc = lane & 15, quad = lane >> 4;
  const int jBase = jb * 128;

  const char* xbf = ws_ro + XBF_OFF;
  // B-tile: linear copy (swizzle preserved: slot&15 == row&15)
  {
    const char* g = xbf + (size_t)jBase * 256 + w * 8192 + lane * 16;
#pragma unroll
    for (int c = 0; c < 8; ++c)
      __builtin_amdgcn_global_load_lds((const gu32*)(g + c * 1024),
                                       (lu32*)(smem + w * 8192 + c * 1024), 16, 0, 0);
  }
  // A-tile: gather this class-chunk's rows (per-lane global addr, wave-uniform LDS base)
  const unsigned short* prm = (const unsigned short*)(ws_ro + PRM_OFF) + t * 128 + chunk * 64;
#pragma unroll
  for (int c = 0; c < 4; ++c) {
    const int slot = w * 16 + c * 4 + (lane >> 4);
    const int r = (slot < active) ? (int)prm[slot] : 0;
    const int p = lane & 15;
    const char* g = xbf + (size_t)r * 256 + ((p ^ (slot & 15) ^ (r & 15)) * 16);
    __builtin_amdgcn_global_load_lds((const gu32*)g,
                                     (lu32*)(smem + 32768 + (w * 16 + c * 4) * 256), 16, 0, 0);
  }
  // coef slice: tab[t][jBase..jBase+128) -> 2 KB
  if (w < 2) {
    const char* g = ws_ro + TAB_OFF + ((size_t)t * N + jBase) * 16 + w * 1024 + lane * 16;
    __builtin_amdgcn_global_load_lds((const gu32*)g, (lu32*)(smem + 49152 + w * 1024), 16, 0, 0);
  }
  __syncthreads();

  const bool act = (w * 16 < active);
  floatx4 acc[8] = {};
  if (act) {
    const char* Abase = smem + 32768 + (w * 16 + lc) * 256;
#pragma unroll
    for (int kb = 0; kb < 4; ++kb) {
      const int pb = ((kb * 4 + quad) ^ lc) * 16;
      const short8 af = *(const short8*)(Abase + pb);
      short8 bfr[8];
#pragma unroll
      for (int tn = 0; tn < 8; ++tn)
        bfr[tn] = *(const short8*)(smem + (tn * 16 + lc) * 256 + pb);
#pragma unroll
      for (int tn = 0; tn < 8; ++tn)
        acc[tn] = __builtin_amdgcn_mfma_f32_16x16x32_bf16(af, bfr[tn], acc[tn], 0, 0, 0);
    }
  }
  __syncthreads();               // tile reads done; overlay Red on B-tile region
  float* Red = (float*)smem;     // [64][81]

  if (act) {
    const float* slice = (const float*)(smem + 49152);   // float4 {gB,gQ,g0,e0} per j_local
    float U[4] = {}, W[4] = {}, V[4] = {}, P1[4] = {}, P2[4] = {};
#pragma unroll
    for (int tn = 0; tn < 8; ++tn) {
      const floatx4 cf = *(const floatx4*)(slice + (tn * 16 + lc) * 4);
      const float gB = cf[0], g0 = cf[2], e0 = cf[3];
#pragma unroll
      for (int reg = 0; reg < 4; ++reg) {
        const float ls = __logf(acc[tn][reg] + 1e-6f);
        const float u = g0 * ls;
        U[reg] += u;
        W[reg] = fmaf(u, ls, W[reg]);
        V[reg] = fmaf(gB, ls, V[reg]);
        const float p = e0 * ls;
        P1[reg] += p;
        P2[reg] = fmaf(p, ls, P2[reg]);
      }
    }
#pragma unroll
    for (int reg = 0; reg < 4; ++reg) {
      const int row = w * 16 + quad * 4 + reg;
      float* dst = Red + row * 81 + lc * 5;
      dst[0] = U[reg]; dst[1] = W[reg]; dst[2] = V[reg]; dst[3] = P1[reg]; dst[4] = P2[reg];
    }
  }
  __syncthreads();

  if (tid < active) {            // active <= 64
    const float* src = Red + tid * 81;
    float s0 = 0.f, s1 = 0.f, s2 = 0.f, s3 = 0.f, s4 = 0.f;
#pragma unroll
    for (int l = 0; l < 16; ++l) {
      s0 += src[l * 5 + 0]; s1 += src[l * 5 + 1]; s2 += src[l * 5 + 2];
      s3 += src[l * 5 + 3]; s4 += src[l * 5 + 4];
    }
    const int gi = (int)prm[tid];
    atomicAdd(&acc5[0 * N + gi], s0);
    atomicAdd(&acc5[1 * N + gi], s1);
    atomicAdd(&acc5[2 * N + gi], s2);
    atomicAdd(&acc5[3 * N + gi], s3);
    atomicAdd(&acc5[4 * N + gi], s4);
  }
}

// ---- phaseB: fold class constants + diag correction, final reduce ----
__global__ __launch_bounds__(256) void logratio_phaseB(
    const char* __restrict__ ws_ro, const int* __restrict__ labels,
    float* out) {
  const int i = blockIdx.x * 256 + threadIdx.x;
  const float* acc5 = (const float*)(ws_ro + ACC_OFF);
  const float U  = acc5[0 * N + i];
  const float W  = acc5[1 * N + i];
  const float V  = acc5[2 * N + i];
  const float P1 = acc5[3 * N + i];
  const float P2 = acc5[4 * N + i];
  const int t = labels[i * 4];
  const float4 S = ((const float4*)(ws_ro + SUM_OFF))[t];   // {Sg0, SgB, SgQ, Ce0}
  const float lsd = ((const float*)(ws_ro + LSD_OFF))[i];
  const float c  = S.w - 1.f;          // pos diagonal always matches
  const float S1 = P1 - lsd;
  const float S2 = P2 - lsd * lsd;
  const float A  = S.x;
  const float Bv = U + S.y;
  const float Cv = W + 2.f * V + S.z;
  float v = S2 * A - 2.f * S1 * Bv + c * Cv;
#pragma unroll
  for (int m = 32; m >= 1; m >>= 1) v += __shfl_xor(v, m, 64);
  __shared__ float wsum[4];
  if ((threadIdx.x & 63) == 0) wsum[threadIdx.x >> 6] = v;
  __syncthreads();
  if (threadIdx.x == 0) atomicAdd(out, wsum[0] + wsum[1] + wsum[2] + wsum[3]);
}

extern "C" void kernel_launch(void* const* d_in, const int* in_sizes, int n_in,
                              void* d_out, int out_size, void* d_ws, size_t ws_size,
                              hipStream_t stream) {
  const float* inputs = (const float*)d_in[0];
  const int* labels = (const int*)d_in[1];
  float* out = (float*)d_out;
  char* ws = (char*)d_ws;

  float Bq[4], Qq[4];
  for (int m = 0; m < 4; ++m) {
    const float lpv = logf(0.1f + 1e-6f) - logf(powf(0.1f, (float)(5 - m)) + 1e-6f);
    Bq[m] = 0.1f * lpv;
    Qq[m] = Bq[m] * Bq[m];
  }

  k1_prep<<<416, 256, 0, stream>>>(inputs, labels, ws, out,
                                   Bq[0], Bq[1], Bq[2], Bq[3],
                                   Qq[0], Qq[1], Qq[2], Qq[3]);
  dim3 grid(32, 128);   // (j-tile, class*2+chunk)
  logratio_phaseA<<<grid, 256, 0, stream>>>(ws, (float*)(ws + ACC_OFF));
  logratio_phaseB<<<N / 256, 256, 0, stream>>>(ws, labels, out);
}

// Round 8
// 79.731 us; speedup vs baseline: 1.4118x; 1.4118x over previous
//
#include <hip/hip_runtime.h>
#include <math.h>

constexpr int N = 4096;
constexpr int D = 128;

// ws layout (bytes)
constexpr size_t XBF_OFF = 0;                        // bf16 X image, 4096 x 256 B, XOR-swizzled (1 MB)
constexpr size_t TAB_OFF = (size_t)1 << 20;          // u8 tab[64][4096] = pattern(e1|e2<<1|e3<<2|e0<<3) (256 KB)
constexpr size_t ACC_OFF = TAB_OFF + 64 * 4096;      // float acc5[5][4096] = {U, W, V, P1, P2} (80 KB)
constexpr size_t LSD_OFF = ACC_OFF + 5 * N * 4;      // float lsdiag[4096] (16 KB)
constexpr size_t SUM_OFF = LSD_OFF + N * 4;          // float4 sums[64] = {Sg0, SgB, SgQ, Ce0} (1 KB)

typedef __attribute__((ext_vector_type(8))) short short8;
typedef __attribute__((ext_vector_type(4))) float floatx4;
typedef __attribute__((address_space(1))) unsigned int gu32;
typedef __attribute__((address_space(3))) unsigned int lu32;

__device__ inline unsigned f2bf(float f) {
  unsigned u = __builtin_bit_cast(unsigned, f);
  return (u + 0x7FFFu + ((u >> 16) & 1u)) >> 16;   // RNE
}

// ---- K1: u8 pattern tab + class sums + bf16 image + diag logs + zeroing ----
__global__ __launch_bounds__(256) void k1_prep(
    const float* __restrict__ X, const int* __restrict__ labels,
    char* __restrict__ ws, float* __restrict__ out,
    float B0, float B1, float B2, float B3,
    float Q0, float Q1, float Q2, float Q3) {
  const int b = blockIdx.x, tid = threadIdx.x;
  if (b < 64) {
    const int t = b;
    __shared__ float red[4][4];
    unsigned char* tabu8 = (unsigned char*)(ws + TAB_OFF) + (size_t)t * N;
    float sg0 = 0.f, sgB = 0.f, sgQ = 0.f, ce0 = 0.f;
#pragma unroll 4
    for (int k = 0; k < 16; ++k) {
      const int j = k * 256 + tid;
      const int4 L = ((const int4*)labels)[j];
      const bool e0 = (t == L.x), e1 = (t == L.y), e2 = (t == L.z), e3 = (t == L.w);
      const bool n1 = e3 && !e2, n2 = e2 && !e1, n3 = e1 && !e0;
      sg0 += (e3 ? 0.f : 1.f) + (n1 ? 1.f : 0.f) + (n2 ? 1.f : 0.f) + (n3 ? 1.f : 0.f);
      sgB += (e3 ? 0.f : B0) + (n1 ? B1 : 0.f) + (n2 ? B2 : 0.f) + (n3 ? B3 : 0.f);
      sgQ += (e3 ? 0.f : Q0) + (n1 ? Q1 : 0.f) + (n2 ? Q2 : 0.f) + (n3 ? Q3 : 0.f);
      ce0 += e0 ? 1.f : 0.f;
      tabu8[j] = (unsigned char)((e1 ? 1u : 0u) | (e2 ? 2u : 0u) | (e3 ? 4u : 0u) | (e0 ? 8u : 0u));
    }
    const int w = tid >> 6, lane = tid & 63;
#pragma unroll
    for (int s = 1; s <= 32; s <<= 1) {
      sg0 += __shfl_xor(sg0, s, 64); sgB += __shfl_xor(sgB, s, 64);
      sgQ += __shfl_xor(sgQ, s, 64); ce0 += __shfl_xor(ce0, s, 64);
    }
    if (lane == 0) { red[w][0] = sg0; red[w][1] = sgB; red[w][2] = sgQ; red[w][3] = ce0; }
    __syncthreads();
    if (tid == 0) {
      float* sums = (float*)(ws + SUM_OFF);
      sums[t * 4 + 0] = red[0][0] + red[1][0] + red[2][0] + red[3][0];
      sums[t * 4 + 1] = red[0][1] + red[1][1] + red[2][1] + red[3][1];
      sums[t * 4 + 2] = red[0][2] + red[1][2] + red[2][2] + red[3][2];
      sums[t * 4 + 3] = red[0][3] + red[1][3] + red[2][3] + red[3][3];
    }
  } else if (b < 320) {
    const int task = (b - 64) * 256 + tid;       // 0 .. 65535
    const int r   = task >> 4;
    const int blk = task & 15;
    const float4 x0 = *(const float4*)&X[r * D + blk * 8];
    const float4 x1 = *(const float4*)&X[r * D + blk * 8 + 4];
    uint4 wv;
    wv.x = f2bf(x0.x) | (f2bf(x0.y) << 16);
    wv.y = f2bf(x0.z) | (f2bf(x0.w) << 16);
    wv.z = f2bf(x1.x) | (f2bf(x1.y) << 16);
    wv.w = f2bf(x1.z) | (f2bf(x1.w) << 16);
    *(uint4*)(ws + XBF_OFF + (size_t)r * 256 + ((blk ^ (r & 15)) * 16)) = wv;
  } else if (b < 336) {
    const int i = (b - 320) * 256 + tid;         // 0 .. 4095
    const float* xr = X + i * D;
    float s = 0.f;
#pragma unroll
    for (int c = 0; c < 32; ++c) {
      const float4 v = ((const float4*)xr)[c];
      s += v.x * v.x + v.y * v.y + v.z * v.z + v.w * v.w;
    }
    ((float*)(ws + LSD_OFF))[i] = __logf(s + 1e-6f);
  } else {
    const int idx = (b - 336) * 256 + tid;       // 0 .. 20479 == 5*4096
    ((float*)(ws + ACC_OFF))[idx] = 0.f;
    if (idx == 0) out[0] = 0.f;
  }
}

// ---- phaseA: MFMA sim tile + palette-decoded epilogue (R5 structure) ----
__global__ __launch_bounds__(512, 4) void logratio_phaseA(
    const char* __restrict__ ws_ro, const int* __restrict__ labels,
    float* acc5, float B0, float B1, float B2, float B3) {

  __shared__ __align__(16) char smem[65792];   // [0,32K) B; [32K,64K) A; [64K,+256) palette; Red overlays [0,41.5K)

  const int tid  = threadIdx.x;
  const int w    = tid >> 6;     // 8 waves
  const int lane = tid & 63;
  const int lc   = lane & 15;
  const int quad = lane >> 4;
  const int jBase = blockIdx.x * 128;
  const int iBase = blockIdx.y * 128;

  // build decode palette: pattern -> {gB, g0, e0f}
  float4* pal = (float4*)(smem + 65536);
  if (tid < 16) {
    const bool e1 = tid & 1, e2 = tid & 2, e3 = tid & 4, e0 = tid & 8;
    const bool n1 = e3 && !e2, n2 = e2 && !e1, n3 = e1 && !e0;
    const float g0 = (e3 ? 0.f : 1.f) + (n1 ? 1.f : 0.f) + (n2 ? 1.f : 0.f) + (n3 ? 1.f : 0.f);
    const float gB = (e3 ? 0.f : B0) + (n1 ? B1 : 0.f) + (n2 ? B2 : 0.f) + (n3 ? B3 : 0.f);
    pal[tid] = make_float4(gB, g0, e0 ? 1.f : 0.f, 0.f);
  }

  const char* xbf = ws_ro + XBF_OFF;
  const char* gB_ = xbf + (size_t)jBase * 256 + w * 4096 + lane * 16;
  const char* gA_ = xbf + (size_t)iBase * 256 + w * 4096 + lane * 16;
#pragma unroll
  for (int c = 0; c < 4; ++c) {
    __builtin_amdgcn_global_load_lds((const gu32*)(gB_ + c * 1024),
                                     (lu32*)(smem + w * 4096 + c * 1024), 16, 0, 0);
    __builtin_amdgcn_global_load_lds((const gu32*)(gA_ + c * 1024),
                                     (lu32*)(smem + 32768 + w * 4096 + c * 1024), 16, 0, 0);
  }

  // row targets while loads fly
  int tis[4];
#pragma unroll
  for (int reg = 0; reg < 4; ++reg)
    tis[reg] = labels[(iBase + w * 16 + quad * 4 + reg) * 4];

  __syncthreads();

  floatx4 acc[8] = {};
  const char* Abase = smem + 32768 + (w * 16 + lc) * 256;
#pragma unroll
  for (int kb = 0; kb < 4; ++kb) {
    const int pb = ((kb * 4 + quad) ^ lc) * 16;
    const short8 af = *(const short8*)(Abase + pb);
    short8 bfr[8];
#pragma unroll
    for (int tn = 0; tn < 8; ++tn)
      bfr[tn] = *(const short8*)(smem + (tn * 16 + lc) * 256 + pb);
#pragma unroll
    for (int tn = 0; tn < 8; ++tn)
      acc[tn] = __builtin_amdgcn_mfma_f32_16x16x32_bf16(af, bfr[tn], acc[tn], 0, 0, 0);
  }

  __syncthreads();              // tile reads done; overlay Red (palette at 64K stays live)
  float* Red = (float*)smem;    // [128][81]

  const unsigned char* tabu8 = (const unsigned char*)(ws_ro + TAB_OFF);
#pragma unroll
  for (int reg = 0; reg < 4; ++reg) {
    const int row = w * 16 + quad * 4 + reg;
    const unsigned char* trow = tabu8 + (size_t)tis[reg] * N + jBase + lc;

    float U = 0.f, W = 0.f, V = 0.f, P1 = 0.f, P2 = 0.f;
#pragma unroll
    for (int tn = 0; tn < 8; ++tn) {
      const unsigned pat = trow[tn * 16];
      const float4 pe = pal[pat];                  // ds_read_b128 broadcast
      const float ls = __logf(acc[tn][reg] + 1e-6f);
      const float u = pe.y * ls;
      U += u;
      W = fmaf(u, ls, W);
      V = fmaf(pe.x, ls, V);
      const float p = pe.z * ls;
      P1 += p;
      P2 = fmaf(p, ls, P2);
    }
    float* dst = Red + row * 81 + lc * 5;
    dst[0] = U; dst[1] = W; dst[2] = V; dst[3] = P1; dst[4] = P2;
  }
  __syncthreads();

  if (tid < 128) {
    const int gi = iBase + tid;
    const float* src = Red + tid * 81;
    float s0 = 0.f, s1 = 0.f, s2 = 0.f, s3 = 0.f, s4 = 0.f;
#pragma unroll
    for (int l = 0; l < 16; ++l) {
      s0 += src[l * 5 + 0]; s1 += src[l * 5 + 1]; s2 += src[l * 5 + 2];
      s3 += src[l * 5 + 3]; s4 += src[l * 5 + 4];
    }
    atomicAdd(&acc5[0 * N + gi], s0);
    atomicAdd(&acc5[1 * N + gi], s1);
    atomicAdd(&acc5[2 * N + gi], s2);
    atomicAdd(&acc5[3 * N + gi], s3);
    atomicAdd(&acc5[4 * N + gi], s4);
  }
}

// ---- phaseB: fold class constants + diag correction, final reduce ----
__global__ __launch_bounds__(256) void logratio_phaseB(
    const char* __restrict__ ws_ro, const int* __restrict__ labels,
    float* out) {
  const int i = blockIdx.x * 256 + threadIdx.x;
  const float* acc5 = (const float*)(ws_ro + ACC_OFF);
  const float U  = acc5[0 * N + i];
  const float W  = acc5[1 * N + i];
  const float V  = acc5[2 * N + i];
  const float P1 = acc5[3 * N + i];
  const float P2 = acc5[4 * N + i];
  const int t = labels[i * 4];
  const float4 S = ((const float4*)(ws_ro + SUM_OFF))[t];   // {Sg0, SgB, SgQ, Ce0}
  const float lsd = ((const float*)(ws_ro + LSD_OFF))[i];
  const float c  = S.w - 1.f;          // pos diagonal always matches
  const float S1 = P1 - lsd;
  const float S2 = P2 - lsd * lsd;
  const float A  = S.x;
  const float Bv = U + S.y;
  const float Cv = W + 2.f * V + S.z;
  float v = S2 * A - 2.f * S1 * Bv + c * Cv;
#pragma unroll
  for (int m = 32; m >= 1; m >>= 1) v += __shfl_xor(v, m, 64);
  __shared__ float wsum[4];
  if ((threadIdx.x & 63) == 0) wsum[threadIdx.x >> 6] = v;
  __syncthreads();
  if (threadIdx.x == 0) atomicAdd(out, wsum[0] + wsum[1] + wsum[2] + wsum[3]);
}

extern "C" void kernel_launch(void* const* d_in, const int* in_sizes, int n_in,
                              void* d_out, int out_size, void* d_ws, size_t ws_size,
                              hipStream_t stream) {
  const float* inputs = (const float*)d_in[0];
  const int* labels = (const int*)d_in[1];
  float* out = (float*)d_out;
  char* ws = (char*)d_ws;

  float Bq[4], Qq[4];
  for (int m = 0; m < 4; ++m) {
    const float lpv = logf(0.1f + 1e-6f) - logf(powf(0.1f, (float)(5 - m)) + 1e-6f);
    Bq[m] = 0.1f * lpv;
    Qq[m] = Bq[m] * Bq[m];
  }

  k1_prep<<<416, 256, 0, stream>>>(inputs, labels, ws, out,
                                   Bq[0], Bq[1], Bq[2], Bq[3],
                                   Qq[0], Qq[1], Qq[2], Qq[3]);
  dim3 grid(N / 128, N / 128);  // 32 x 32
  logratio_phaseA<<<grid, 512, 0, stream>>>(ws, labels, (float*)(ws + ACC_OFF),
                                            Bq[0], Bq[1], Bq[2], Bq[3]);
  logratio_phaseB<<<N / 256, 256, 0, stream>>>(ws, labels, out);
}